// Round 12
// baseline (244.597 us; speedup 1.0000x reference)
//
#include <hip/hip_runtime.h>
#include <hip/hip_bf16.h>
#include <stdint.h>

#define AS1 __attribute__((address_space(1)))
#define AS3 __attribute__((address_space(3)))

typedef __bf16 bf16_t;
typedef __bf16 bf16x8 __attribute__((ext_vector_type(8)));
typedef float f32x4 __attribute__((ext_vector_type(4)));
typedef float f32x16 __attribute__((ext_vector_type(16)));

static constexpr int Bsz = 2, T = 2048, Cdim = 2048, NH = 16, DH = 128;
static constexpr int M  = Bsz * T;    // 4096
static constexpr int N1 = 3 * Cdim;   // 6144
static constexpr int K1 = Cdim;       // 2048

__device__ __forceinline__ unsigned short f2bf(float f) {
  unsigned u = __float_as_uint(f);
  u += 0x7fffu + ((u >> 16) & 1u);
  return (unsigned short)(u >> 16);
}

__device__ __forceinline__ void gload_lds16(const bf16_t* g, void* l) {
  __builtin_amdgcn_global_load_lds((AS1 const void*)g, (AS3 void*)l, 16, 0, 0);
}

__device__ __forceinline__ float ex2(float x) {
  float r; asm("v_exp_f32 %0, %1" : "=v"(r) : "v"(x)); return r;
}
__device__ __forceinline__ unsigned pk2(float a, float b) {
  unsigned r; asm("v_cvt_pk_bf16_f32 %0, %1, %2" : "=v"(r) : "v"(a), "v"(b)); return r;
}

// ---------------- fused preamble: cvt(x) + transpose(Wa) + transpose(Wp) ----------------
__global__ __launch_bounds__(256) void preamble_kernel(const float* __restrict__ x,
                                                       const float* __restrict__ Wa,
                                                       const float* __restrict__ Wp,
                                                       unsigned short* __restrict__ xb,
                                                       unsigned short* __restrict__ WaT,
                                                       unsigned short* __restrict__ WpT) {
  __shared__ float tile[32][33];
  const int blk = blockIdx.x;
  const int tid = threadIdx.x;
  if (blk < 8192) {
    int i = blk * 1024 + tid * 4;
    float4 v = *(const float4*)(x + i);
    ushort4 o;
    o.x = f2bf(v.x); o.y = f2bf(v.y); o.z = f2bf(v.z); o.w = f2bf(v.w);
    *(ushort4*)(xb + i) = o;
    return;
  }
  const float* in;
  unsigned short* out;
  int Nn, bi;
  if (blk < 20480) { in = Wa; out = WaT; Nn = N1;   bi = blk - 8192;  }
  else             { in = Wp; out = WpT; Nn = Cdim; bi = blk - 20480; }
  const int ntiles = Nn >> 5;
  const int n0 = (bi % ntiles) * 32, k0 = (bi / ntiles) * 32;
  const int tx = tid & 31, ty = tid >> 5;  // 32 x 8
#pragma unroll
  for (int i = 0; i < 32; i += 8)
    tile[ty + i][tx] = in[(size_t)(k0 + ty + i) * Nn + n0 + tx];
  __syncthreads();
#pragma unroll
  for (int i = 0; i < 32; i += 8)
    out[(size_t)(n0 + ty + i) * K1 + k0 + tx] = f2bf(tile[tx][ty + i]);
}

// ---------------- gemm8p: m201-style 8-phase 256x256 GEMM (qkv), DE-PINNED ----------------
// Identical schedule to R10 but with ZERO sched_barrier(0) (template-faithful;
// m141 showed order-pinning costs ~40%). BK=64, 8 waves (2M x 4N), per-wave
// 128x64, LDS 128 KiB = 2 dbuf x (A 2x16KB + B 2x16KB).
// Per phase: {ds-read subtile || stage 1 half-tile} -> barrier -> lgkmcnt(0) ->
// setprio+16 MFMA -> [vmcnt(4) at ph3/ph7] -> barrier.
template <int MODE>
__global__ __launch_bounds__(512, 1) void gemm8p(const bf16_t* __restrict__ A,
                                                 const bf16_t* __restrict__ BT,
                                                 void* __restrict__ Cp,
                                                 int Nn, int Kk) {
  __shared__ __align__(16) char ldsmem[131072];
  char* ldsb = ldsmem;
  const char* sb0 = ldsmem;
  const char* sb1 = ldsmem + 65536;

  const int tid = threadIdx.x;
  const int lane = tid & 63;
  const int wid = tid >> 6;
  const int lq = lane & 15, lk = lane >> 4;
  const int wr = wid >> 2, wc = wid & 3;

  // L2-aware XCD mapping
  const int bid = blockIdx.x;
  const int xcd = bid & 7;
  const int j = bid >> 3;
  const int r = j & 15, s5 = j >> 4;
  const int tn = s5 * 8 + (r & 7);
  const int tm = xcd * 2 + (r >> 3);

  f32x4 acc[8][4] = {};
  bf16x8 afA[8], bf01[4], bf23[4];

  // ---- staging source (inverse-swizzled global, linear LDS dest) ----
  const int r0 = tid >> 3;
  const int c0 = (tid * 16) & 127;
  const int csw = (c0 ^ ((r0 & 7) << 4)) >> 1;
  const bf16_t* Agp = A + (size_t)(tm * 256 + r0) * Kk + csw;
  const bf16_t* Bgp = BT + (size_t)(tn * 256 + r0) * Kk + csw;

  auto stA = [&](int h, int kt, int d) {
    char* db = ldsb + d * 65536 + h * 16384 + tid * 16;
    const bf16_t* s = Agp + (size_t)(h * 128) * Kk + (size_t)kt * 64;
    gload_lds16(s, db);
    gload_lds16(s + (size_t)64 * Kk, db + 8192);
  };
  auto stB = [&](int h, int kt, int d) {
    char* db = ldsb + 32768 + d * 65536 + h * 16384 + tid * 16;
    const bf16_t* s = Bgp + (size_t)(h * 128) * Kk + (size_t)kt * 64;
    gload_lds16(s, db);
    gload_lds16(s + (size_t)64 * Kk, db + 8192);
  };

  // ---- ds-read fragments (swizzled) ----
  auto rdA = [&](const char* sb, int h) {
#pragma unroll
    for (int m = 0; m < 4; ++m) {
      const int rA = wr * 128 + (h * 4 + m) * 16 + lq;
      const int sw = (rA & 7) << 4;
      const char* rp = sb + rA * 128;
      afA[m * 2 + 0] = *(const bf16x8*)(rp + ((lk * 16) ^ sw));
      afA[m * 2 + 1] = *(const bf16x8*)(rp + ((64 + lk * 16) ^ sw));
    }
  };
  auto rdB = [&](const char* sb, int nh, bf16x8* bfr) {
#pragma unroll
    for (int n = 0; n < 2; ++n) {
      const int rB = wc * 64 + (nh * 2 + n) * 16 + lq;
      const int sw = (rB & 7) << 4;
      const char* rp = sb + 32768 + rB * 128;
      bfr[n * 2 + 0] = *(const bf16x8*)(rp + ((lk * 16) ^ sw));
      bfr[n * 2 + 1] = *(const bf16x8*)(rp + ((64 + lk * 16) ^ sw));
    }
  };
  auto mmq = [&](const bf16x8* bfr, int mh, int nh) {
#pragma unroll
    for (int m = 0; m < 4; ++m)
#pragma unroll
      for (int n = 0; n < 2; ++n)
#pragma unroll
        for (int ks = 0; ks < 2; ++ks)
          acc[mh * 4 + m][nh * 2 + n] = __builtin_amdgcn_mfma_f32_16x16x32_bf16(
              afA[m * 2 + ks], bfr[n * 2 + ks], acc[mh * 4 + m][nh * 2 + n], 0, 0, 0);
  };

#define PH8(RD, ST, MH, NH, BF, VMSTR)                          \
  {                                                             \
    RD;                                                         \
    ST;                                                         \
    __builtin_amdgcn_s_barrier();                               \
    asm volatile("s_waitcnt lgkmcnt(0)" ::: "memory");          \
    __builtin_amdgcn_s_setprio(1);                              \
    mmq(BF, MH, NH);                                            \
    __builtin_amdgcn_s_setprio(0);                              \
    asm volatile(VMSTR ::: "memory");                           \
    __builtin_amdgcn_s_barrier();                               \
  }

#define ITER8(T1, T2, T3, STEN, VM3, VM7)                                        \
  PH8((rdA(sb0, 0), rdB(sb0, 0, bf01)), stA(0, (T1), 1), 0, 0, bf01, "")         \
  PH8(rdB(sb0, 1, bf23),                stA(1, (T1), 1), 0, 1, bf23, "")         \
  PH8(rdA(sb0, 1),                      if (STEN) stB(0, (T2), 0), 1, 0, bf01, "") \
  PH8((void)0,                          if (STEN) stB(1, (T2), 0), 1, 1, bf23, VM3) \
  PH8((rdA(sb1, 0), rdB(sb1, 0, bf01)), if (STEN) stA(0, (T2), 0), 0, 0, bf01, "") \
  PH8(rdB(sb1, 1, bf23),                if (STEN) stA(1, (T2), 0), 0, 1, bf23, "") \
  PH8(rdA(sb1, 1),                      if (STEN) stB(0, (T3), 1), 1, 0, bf01, "") \
  PH8((void)0,                          if (STEN) stB(1, (T3), 1), 1, 1, bf23, VM7)

  // ---- prologue: dbuf0 <- tile0 (B0,B1,A0,A1), dbuf1 <- tile1 (B0,B1) ----
  stB(0, 0, 0); stB(1, 0, 0); stA(0, 0, 0); stA(1, 0, 0);
  stB(0, 1, 1); stB(1, 1, 1);
  asm volatile("s_waitcnt vmcnt(4)" ::: "memory");
  __builtin_amdgcn_s_barrier();

  // ---- main loop: 32 K-tiles of 64, 16 iterations ----
  for (int i = 0; i < 15; ++i) {
    const int t1 = 2 * i + 1, t2 = 2 * i + 2, t3 = 2 * i + 3;
    ITER8(t1, t2, t3, 1, "s_waitcnt vmcnt(4)", "s_waitcnt vmcnt(4)")
  }
  {
    const int t1 = 31, t2 = 0, t3 = 0;
    ITER8(t1, t2, t3, 0, "s_waitcnt vmcnt(0)", "")
  }
#undef ITER8
#undef PH8

  // ---- epilogue ----
  if (MODE == 1 && tn >= 16) {
    unsigned short* q16 = (unsigned short*)Cp;
#pragma unroll
    for (int m = 0; m < 8; ++m)
#pragma unroll
      for (int n = 0; n < 4; ++n) {
        int row = tm * 256 + wr * 128 + m * 16 + lk * 4;
        int b_ = row >> 11, t0 = row & 2047;
        int c = tn * 256 - 4096 + wc * 64 + n * 16 + lq;
        ushort4 o;
        o.x = f2bf(acc[m][n][0]); o.y = f2bf(acc[m][n][1]);
        o.z = f2bf(acc[m][n][2]); o.w = f2bf(acc[m][n][3]);
        *(ushort4*)(q16 + (size_t)(b_ * 2048 + c) * N1 + 4096 + t0) = o;
      }
  } else {
#pragma unroll
    for (int m = 0; m < 8; ++m)
#pragma unroll
      for (int n = 0; n < 4; ++n)
#pragma unroll
        for (int r2 = 0; r2 < 4; ++r2) {
          int row = tm * 256 + wr * 128 + m * 16 + lk * 4 + r2;
          int col = tn * 256 + wc * 64 + n * 16 + lq;
          if (MODE == 1)
            ((unsigned short*)Cp)[(size_t)row * Nn + col] = f2bf(acc[m][n][r2]);
          else
            ((float*)Cp)[(size_t)row * Nn + col] = acc[m][n][r2];
        }
  }
}

// ---------------- gemm_s: 128x256, single-barrier tile body (proj GEMM) ----------------
__global__ __launch_bounds__(512, 4) void gemm_s(const bf16_t* __restrict__ A,
                                                 const bf16_t* __restrict__ BT,
                                                 float* __restrict__ Cp,
                                                 int Nn, int Kk) {
  constexpr int SLOT = 24576;
  __shared__ __align__(16) char ldsmem[3 * SLOT];
  char* ldsb = ldsmem;

  const int tid = threadIdx.x;
  const int wid = tid >> 6, lane = tid & 63;
  const int lq = lane & 15, lk = lane >> 4;
  const int wr = wid >> 2, wc = wid & 3;

  const int bid = blockIdx.x;
  const int xcd = bid & 7;
  const int j = bid >> 3;
  const int r = j & 31, s5 = j >> 5;
  const int tn = s5 * 8 + (r & 7);
  const int tm = xcd * 4 + (r >> 3);

  f32x4 acc[4][4] = {};

  int aoff[4], boff[4];
#pragma unroll
  for (int m = 0; m < 4; ++m) {
    int row = wr * 64 + m * 16 + lq;
    aoff[m] = row * 64 + ((lk * 16) ^ (((row >> 1) & 3) << 4));
  }
#pragma unroll
  for (int n = 0; n < 4; ++n) {
    int brow = wc * 64 + n * 16 + lq;
    boff[n] = 8192 + brow * 64 + ((lk * 16) ^ (((brow >> 1) & 3) << 4));
  }

  const int pA = wid * 1024 + lane * 16;
  const int arow = pA >> 6;
  const int acsw = (pA & 63) ^ (((arow >> 1) & 3) << 4);
  const bf16_t* Ags = A + (size_t)(tm * 128 + arow) * Kk + (acsw >> 1);

  const int pB0 = wid * 1024 + lane * 16;
  const int brow0 = pB0 >> 6;
  const int bcsw0 = (pB0 & 63) ^ (((brow0 >> 1) & 3) << 4);
  const bf16_t* Bgs0 = BT + (size_t)(tn * 256 + brow0) * Kk + (bcsw0 >> 1);

  const int pB1 = 8192 + wid * 1024 + lane * 16;
  const int brow1 = pB1 >> 6;  // 128..255
  const int bcsw1 = (pB1 & 63) ^ (((brow1 >> 1) & 3) << 4);
  const bf16_t* Bgs1 = BT + (size_t)(tn * 256 + brow1) * Kk + (bcsw1 >> 1);

  const int ldsA = wid * 1024;
  const int ldsB0 = 8192 + wid * 1024;
  const int ldsB1 = 16384 + wid * 1024;

  auto stage = [&](int kt, int slot) {
    char* db = ldsb + slot * SLOT;
    gload_lds16(Ags + (size_t)kt * 32, db + ldsA);
    gload_lds16(Bgs0 + (size_t)kt * 32, db + ldsB0);
    gload_lds16(Bgs1 + (size_t)kt * 32, db + ldsB1);
  };

  const int nk = Kk >> 5;

  stage(0, 0); stage(1, 1);
  asm volatile("s_waitcnt vmcnt(3)" ::: "memory");
  __builtin_amdgcn_s_barrier();

#define STILE(KT, SLOT0, SLOT2, STAGE_EN, VM)                                    \
  {                                                                              \
    const char* sb = ldsb + (SLOT0) * SLOT;                                      \
    bf16x8 af[4], bfv[4];                                                        \
    _Pragma("unroll") for (int m = 0; m < 4; ++m)                                \
      af[m] = *(const bf16x8*)(sb + aoff[m]);                                    \
    _Pragma("unroll") for (int n = 0; n < 4; ++n)                                \
      bfv[n] = *(const bf16x8*)(sb + boff[n]);                                   \
    if (STAGE_EN) stage((KT) + 2, (SLOT2));                                      \
    _Pragma("unroll") for (int m = 0; m < 4; ++m)                                \
      _Pragma("unroll") for (int n = 0; n < 4; ++n)                              \
        acc[m][n] =                                                              \
            __builtin_amdgcn_mfma_f32_16x16x32_bf16(af[m], bfv[n], acc[m][n], 0, 0, 0); \
    asm volatile("s_waitcnt vmcnt(" #VM ")" ::: "memory");                       \
    __builtin_amdgcn_s_barrier();                                                \
  }

  {
    int c0 = 0;
    for (int kt = 0; kt < nk - 2; ++kt) {
      const int c2 = (c0 >= 1) ? (c0 - 1) : (c0 + 2);  // (c0+2)%3
      STILE(kt, c0, c2, 1, 3);
      c0 = (c0 >= 2) ? 0 : (c0 + 1);
    }
    STILE(nk - 2, c0, 0, 0, 0);
    c0 = (c0 >= 2) ? 0 : (c0 + 1);
    STILE(nk - 1, c0, 0, 0, 0);
  }
#undef STILE

#pragma unroll
  for (int m = 0; m < 4; ++m)
#pragma unroll
    for (int n = 0; n < 4; ++n)
#pragma unroll
      for (int r2 = 0; r2 < 4; ++r2) {
        int row = tm * 128 + wr * 64 + m * 16 + lk * 4 + r2;
        int col = tn * 256 + wc * 64 + n * 16 + lq;
        Cp[(size_t)row * Nn + col] = acc[m][n][r2];
      }
}

// ---------------- causal flash attention (unchanged) ----------------
__global__ __launch_bounds__(512, 1) void attn_kernel(const bf16_t* __restrict__ qkv,
                                                      unsigned short* __restrict__ y) {
  __shared__ __align__(16) char lds[98304];  // 3 slots x (K 16KB + V 16KB)
  const int tid = threadIdx.x;
  const int wid = tid >> 6, lane = tid & 63;
  const int l31 = lane & 31, hi = lane >> 5;
  const int hi16 = hi << 4;
  const int bh = blockIdx.x;
  const int g = blockIdx.y;
  const int b = bh >> 4, h = bh & 15;
  const float SC2 = 0.12751879868954096f;  // (1/sqrt(128)) * log2(e)

  const int grp = (wid < 4) ? g : (15 - g);
  const int qlo = grp * 128 + (wid & 3) * 32;
  const int qidx = qlo + l31;
  const int nt = 2 * (15 - g) + 2;
  const size_t rowbase = (size_t)(b * T) * N1;

  bf16x8 qf[8];
  {
    const bf16_t* Qg = qkv + rowbase + (size_t)qidx * N1 + h * DH + hi * 8;
#pragma unroll
    for (int kk = 0; kk < 8; ++kk) qf[kk] = *(const bf16x8*)(Qg + kk * 16);
  }

  const bf16_t* Kg0 = qkv + rowbase + Cdim + h * DH;
  const bf16_t* Vg0 = qkv + (size_t)(b * 2048 + h * DH) * N1 + 2 * Cdim;
  const int p0 = wid * 1024 + lane * 16;
  const int p1 = 8192 + wid * 1024 + lane * 16;
  const int kr0 = p0 >> 8, kr1 = p1 >> 8;
  const bf16_t* KsA = Kg0 + (size_t)kr0 * N1 + ((((p0 & 255) ^ ((kr0 & 15) << 4))) >> 1);
  const bf16_t* KsB = Kg0 + (size_t)kr1 * N1 + ((((p1 & 255) ^ ((kr1 & 15) << 4))) >> 1);
  const int vr0 = p0 >> 7, vr1 = p1 >> 7;
  const bf16_t* VsA = Vg0 + (size_t)vr0 * N1 + ((((p0 & 127) ^ ((vr0 & 7) << 4))) >> 1);
  const bf16_t* VsB = Vg0 + (size_t)vr1 * N1 + ((((p1 & 127) ^ ((vr1 & 7) << 4))) >> 1);
  const int dstoff = wid * 1024;

  auto stage = [&](int tt, int slot) {
    char* Kd = lds + slot * 32768;
    char* Vd = Kd + 16384;
    const size_t ko = (size_t)(tt * 64) * N1;
    const int vo = tt * 64;
    gload_lds16(KsA + ko, Kd + dstoff);
    gload_lds16(KsB + ko, Kd + 8192 + dstoff);
    gload_lds16(VsA + vo, Vd + dstoff);
    gload_lds16(VsB + vo, Vd + 8192 + dstoff);
  };

  f32x16 oacc[4] = {};
  float mrow = -1e30f, lrow = 0.f;

  stage(0, 0); stage(1, 1);
  asm volatile("s_waitcnt vmcnt(4)" ::: "memory");
  __builtin_amdgcn_s_barrier();

  int cs = 0;
  for (int t = 0; t < nt; ++t) {
    const int kv0 = t * 64;
    if (t + 2 < nt) {
      const int s2 = (cs >= 1) ? (cs - 1) : (cs + 2);
      stage(t + 2, s2);
    }

    if (kv0 <= qlo + 31) {
      f32x16 s0 = {}, s1 = {};
      {
        const char* Kb = lds + cs * 32768;
        const char* krow0 = Kb + l31 * 256;
        const char* krow1 = Kb + (32 + l31) * 256;
        const int sw0 = (l31 & 15) << 4;
#pragma unroll
        for (int kk = 0; kk < 8; ++kk) {
          bf16x8 kf0 = *(const bf16x8*)(krow0 + ((kk * 32 + hi16) ^ sw0));
          bf16x8 kf1 = *(const bf16x8*)(krow1 + ((kk * 32 + hi16) ^ sw0));
          s0 = __builtin_amdgcn_mfma_f32_32x32x16_bf16(kf0, qf[kk], s0, 0, 0, 0);
          s1 = __builtin_amdgcn_mfma_f32_32x32x16_bf16(kf1, qf[kk], s1, 0, 0, 0);
        }
      }
      float sv[32];
#pragma unroll
      for (int r = 0; r < 16; ++r) { sv[r] = s0[r]; sv[16 + r] = s1[r]; }
      if (kv0 + 63 > qlo) {
#pragma unroll
        for (int r = 0; r < 16; ++r) {
          const int roff = (r & 3) + 8 * (r >> 2);
          if (kv0 + roff + 4 * hi > qidx) sv[r] = -1e30f;
          if (kv0 + 32 + roff + 4 * hi > qidx) sv[16 + r] = -1e30f;
        }
      }
      float mx = sv[0];
#pragma unroll
      for (int i = 1; i < 32; ++i) mx = fmaxf(mx, sv[i]);
      mx = fmaxf(mx, __shfl_xor(mx, 32));
      const float mn = fmaxf(mrow, mx);
      const float osc = ex2((mrow - mn) * SC2);
      mrow = mn;
      const float mn2 = mn * SC2;
#pragma unroll
      for (int db = 0; db < 4; ++db) oacc[db] *= osc;
      float srow = 0.f;
#pragma unroll
      for (int i = 0; i < 32; ++i) {
        float p = ex2(fmaf(sv[i], SC2, -mn2));
        sv[i] = p;
        srow += p;
      }
      srow += __shfl_xor(srow, 32);
      lrow = lrow * osc + srow;
      bf16x8 pb[4];
#pragma unroll
      for (int s4 = 0; s4 < 4; ++s4) {
        const int base = (s4 >> 1) * 16 + (s4 & 1) * 8;
        unsigned x0 = pk2(sv[base + 0], sv[base + 1]);
        unsigned x1 = pk2(sv[base + 2], sv[base + 3]);
        unsigned y0 = pk2(sv[base + 4], sv[base + 5]);
        unsigned y1 = pk2(sv[base + 6], sv[base + 7]);
        unsigned e0 = (unsigned)__shfl_xor((int)(hi ? x0 : y0), 32);
        unsigned e1 = (unsigned)__shfl_xor((int)(hi ? x1 : y1), 32);
        union { unsigned u[4]; bf16x8 v; } pbu;
        pbu.u[0] = hi ? e0 : x0;
        pbu.u[1] = hi ? e1 : x1;
        pbu.u[2] = hi ? y0 : e0;
        pbu.u[3] = hi ? y1 : e1;
        pb[s4] = pbu.v;
      }
      {
        const char* Vb = lds + cs * 32768 + 16384;
#pragma unroll
        for (int db = 0; db < 4; ++db) {
          const int vrow = db * 32 + l31;
          const char* vr = Vb + vrow * 128;
          const int swv = (vrow & 7) << 4;
#pragma unroll
          for (int s4 = 0; s4 < 4; ++s4) {
            bf16x8 vf = *(const bf16x8*)(vr + ((s4 * 32 + hi16) ^ swv));
            oacc[db] = __builtin_amdgcn_mfma_f32_32x32x16_bf16(vf, pb[s4], oacc[db], 0, 0, 0);
          }
        }
      }
    }

    asm volatile("s_waitcnt vmcnt(4)" ::: "memory");
    __builtin_amdgcn_s_barrier();
    cs = (cs >= 2) ? 0 : (cs + 1);
  }

  const float inv = 1.0f / lrow;
  char* eb = lds + wid * 8192;
#pragma unroll
  for (int db = 0; db < 4; ++db)
#pragma unroll
    for (int r = 0; r < 16; ++r) {
      const int d = db * 32 + (r & 3) + 8 * (r >> 2) + 4 * hi;
      const int off = l31 * 256 + ((d * 2) ^ ((l31 & 15) << 4));
      *(unsigned short*)(eb + off) = f2bf(oacc[db][r] * inv);
    }
  asm volatile("s_waitcnt lgkmcnt(0)" ::: "memory");
  __builtin_amdgcn_sched_barrier(0);
  {
    unsigned short* yr = y + (size_t)(b * T + qlo + l31) * Cdim + h * DH;
#pragma unroll
    for (int rr = 0; rr < 8; ++rr) {
      const int c = hi * 8 + rr;
      bf16x8 v = *(const bf16x8*)(eb + l31 * 256 + ((c * 16) ^ ((l31 & 15) << 4)));
      *(bf16x8*)(yr + c * 8) = v;
    }
  }
}

extern "C" void kernel_launch(void* const* d_in, const int* in_sizes, int n_in,
                              void* d_out, int out_size, void* d_ws, size_t ws_size,
                              hipStream_t stream) {
  const float* x  = (const float*)d_in[0];
  const float* Wa = (const float*)d_in[1];
  const float* Wp = (const float*)d_in[2];
  float* out = (float*)d_out;
  char* ws = (char*)d_ws;

  size_t o0 = 0;                            // xb : M*K1 bf16
  size_t o1 = o0 + (size_t)M * K1 * 2;      // WaT: N1*K1 bf16
  size_t o2 = o1 + (size_t)N1 * K1 * 2;     // qkv: M*N1 bf16 (V stripe holds Vt remap)
  size_t o3 = o2 + (size_t)M * N1 * 2;      // yb : M*C bf16
  size_t o4 = o3 + (size_t)M * Cdim * 2;    // WpT: C*C bf16

  unsigned short* xb   = (unsigned short*)(ws + o0);
  unsigned short* WaT  = (unsigned short*)(ws + o1);
  unsigned short* qkvb = (unsigned short*)(ws + o2);
  unsigned short* yb   = (unsigned short*)(ws + o3);
  unsigned short* WpT  = (unsigned short*)(ws + o4);

  preamble_kernel<<<dim3(24576), dim3(256), 0, stream>>>(x, Wa, Wp, xb, WaT, WpT);

  // qkv GEMM: 256x256 8-phase (de-pinned), grid = 16*24 = 384 blocks
  gemm8p<1><<<dim3((M / 256) * (N1 / 256)), dim3(512), 0, stream>>>(
      (const bf16_t*)xb, (const bf16_t*)WaT, (void*)qkvb, N1, K1);

  attn_kernel<<<dim3(Bsz * NH, 8), dim3(512), 0, stream>>>(
      (const bf16_t*)qkvb, yb);

  // proj GEMM: 128x256 tiles single-barrier, grid = 32*8 = 256 blocks
  gemm_s<<<dim3((M / 128) * (Cdim / 256)), dim3(512), 0, stream>>>(
      (const bf16_t*)yb, (const bf16_t*)WpT, out, Cdim, K1);
}

// Round 13
// 238.501 us; speedup vs baseline: 1.0256x; 1.0256x over previous
//
#include <hip/hip_runtime.h>
#include <hip/hip_bf16.h>
#include <stdint.h>

#define AS1 __attribute__((address_space(1)))
#define AS3 __attribute__((address_space(3)))

typedef __bf16 bf16_t;
typedef __bf16 bf16x8 __attribute__((ext_vector_type(8)));
typedef float f32x4 __attribute__((ext_vector_type(4)));
typedef float f32x16 __attribute__((ext_vector_type(16)));

static constexpr int Bsz = 2, T = 2048, Cdim = 2048, NH = 16, DH = 128;
static constexpr int M  = Bsz * T;    // 4096
static constexpr int N1 = 3 * Cdim;   // 6144
static constexpr int K1 = Cdim;       // 2048

__device__ __forceinline__ unsigned short f2bf(float f) {
  unsigned u = __float_as_uint(f);
  u += 0x7fffu + ((u >> 16) & 1u);
  return (unsigned short)(u >> 16);
}

__device__ __forceinline__ void gload_lds16(const bf16_t* g, void* l) {
  __builtin_amdgcn_global_load_lds((AS1 const void*)g, (AS3 void*)l, 16, 0, 0);
}

__device__ __forceinline__ float ex2(float x) {
  float r; asm("v_exp_f32 %0, %1" : "=v"(r) : "v"(x)); return r;
}
__device__ __forceinline__ unsigned pk2(float a, float b) {
  unsigned r; asm("v_cvt_pk_bf16_f32 %0, %1, %2" : "=v"(r) : "v"(a), "v"(b)); return r;
}

// ---------------- fused preamble v2: cvt(x) + transpose(Wa) + transpose(Wp) ----------------
// blocks [0,8192): cvt x (float4->ushort4).
// [8192,14336): Wa^T, [14336,16384): Wp^T -- 64k x 32n tiles, float2/ushort2
// vectorized transpose writes (2x fewer store instrs vs scalar ushort).
__global__ __launch_bounds__(256) void preamble_kernel(const float* __restrict__ x,
                                                       const float* __restrict__ Wa,
                                                       const float* __restrict__ Wp,
                                                       unsigned short* __restrict__ xb,
                                                       unsigned short* __restrict__ WaT,
                                                       unsigned short* __restrict__ WpT) {
  __shared__ float tile[32][66];  // [n][k], pad 66 -> conflict-free both phases
  const int blk = blockIdx.x;
  const int tid = threadIdx.x;
  if (blk < 8192) {
    int i = blk * 1024 + tid * 4;
    float4 v = *(const float4*)(x + i);
    ushort4 o;
    o.x = f2bf(v.x); o.y = f2bf(v.y); o.z = f2bf(v.z); o.w = f2bf(v.w);
    *(ushort4*)(xb + i) = o;
    return;
  }
  const float* in;
  unsigned short* out;
  int Nn, bi;
  if (blk < 14336) { in = Wa; out = WaT; Nn = N1;   bi = blk - 8192;  }
  else             { in = Wp; out = WpT; Nn = Cdim; bi = blk - 14336; }
  const int ntn = Nn >> 5;                 // n-tiles per k-band
  const int n0 = (bi % ntn) * 32;
  const int k0 = (bi / ntn) * 64;
  const int tx = tid & 31, ty = tid >> 5;  // read: 8 k-rows/iter, 32 n cols
#pragma unroll
  for (int i = 0; i < 64; i += 8)
    tile[tx][ty + i] = in[(size_t)(k0 + ty + i) * Nn + n0 + tx];
  __syncthreads();
  const int kp = tid & 31, ny = tid >> 5;  // write: n-row ny+8i, k-pair kp
#pragma unroll
  for (int i = 0; i < 32; i += 8) {
    const int nn = ny + i;
    float2 v = *(const float2*)&tile[nn][2 * kp];
    ushort2 o;
    o.x = f2bf(v.x); o.y = f2bf(v.y);
    *(ushort2*)(out + (size_t)(n0 + nn) * K1 + k0 + 2 * kp) = o;
  }
}

// ---------------- gemm_q: 256x256 tile, per-wave 128x64 (qkv GEMM, R9 exact) ----------------
// BK=32, 8 waves (2M x 4N). Ring-3 LDS slots of 32KB (96 KiB), prefetch 2 tiles
// ahead, counted vmcnt(4), ONE barrier per tile. XOR-swizzled LDS, XCD mapping.
// V-region (tn>=16) written transposed into qkv V stripe (b*2048+c)*6144+4096+t.
__global__ __launch_bounds__(512, 2) void gemm_q(const bf16_t* __restrict__ A,
                                                 const bf16_t* __restrict__ BT,
                                                 void* __restrict__ Cp,
                                                 int Nn, int Kk) {
  constexpr int SLOT = 32768;  // A 16KB @0, B 16KB @16384
  __shared__ __align__(16) char ldsmem[3 * SLOT];
  char* ldsb = ldsmem;

  const int tid = threadIdx.x;
  const int lane = tid & 63;
  const int wid = tid >> 6;
  const int lq = lane & 15, lk = lane >> 4;
  const int wr = wid >> 2, wc = wid & 3;

  const int bid = blockIdx.x;
  const int xcd = bid & 7;
  const int j = bid >> 3;
  const int r = j & 15, s5 = j >> 4;
  const int tn = s5 * 8 + (r & 7);
  const int tm = xcd * 2 + (r >> 3);

  f32x4 acc[8][4] = {};

  int aoff[8], boff[4];
#pragma unroll
  for (int m = 0; m < 8; ++m) {
    int row = wr * 128 + m * 16 + lq;
    aoff[m] = row * 64 + ((lk * 16) ^ (((row >> 1) & 3) << 4));
  }
#pragma unroll
  for (int n = 0; n < 4; ++n) {
    int brow = wc * 64 + n * 16 + lq;
    boff[n] = 16384 + brow * 64 + ((lk * 16) ^ (((brow >> 1) & 3) << 4));
  }

  const int pA0 = tid * 16;
  const int ar0 = pA0 >> 6;
  const int ac0 = (pA0 & 63) ^ (((ar0 >> 1) & 3) << 4);
  const bf16_t* Ags0 = A + (size_t)(tm * 256 + ar0) * Kk + (ac0 >> 1);
  const int pA1 = 8192 + tid * 16;
  const int ar1 = pA1 >> 6;  // 128..255
  const int ac1 = (pA1 & 63) ^ (((ar1 >> 1) & 3) << 4);
  const bf16_t* Ags1 = A + (size_t)(tm * 256 + ar1) * Kk + (ac1 >> 1);
  const bf16_t* Bgs0 = BT + (size_t)(tn * 256 + ar0) * Kk + (ac0 >> 1);
  const bf16_t* Bgs1 = BT + (size_t)(tn * 256 + ar1) * Kk + (ac1 >> 1);

  auto stage = [&](int kt, int slot) {
    char* db = ldsb + slot * SLOT;
    gload_lds16(Ags0 + (size_t)kt * 32, db + tid * 16);
    gload_lds16(Ags1 + (size_t)kt * 32, db + 8192 + tid * 16);
    gload_lds16(Bgs0 + (size_t)kt * 32, db + 16384 + tid * 16);
    gload_lds16(Bgs1 + (size_t)kt * 32, db + 24576 + tid * 16);
  };

  const int nk = Kk >> 5;  // 64

  stage(0, 0); stage(1, 1);
  asm volatile("s_waitcnt vmcnt(4)" ::: "memory");
  __builtin_amdgcn_s_barrier();

#define QTILE(KT, SLOT0, SLOT2, STAGE_EN, VM)                                    \
  {                                                                              \
    const char* sb = ldsb + (SLOT0) * SLOT;                                      \
    bf16x8 af[8], bfv[4];                                                        \
    _Pragma("unroll") for (int m = 0; m < 8; ++m)                                \
      af[m] = *(const bf16x8*)(sb + aoff[m]);                                    \
    _Pragma("unroll") for (int n = 0; n < 4; ++n)                                \
      bfv[n] = *(const bf16x8*)(sb + boff[n]);                                   \
    if (STAGE_EN) stage((KT) + 2, (SLOT2));                                      \
    _Pragma("unroll") for (int m = 0; m < 8; ++m)                                \
      _Pragma("unroll") for (int n = 0; n < 4; ++n)                              \
        acc[m][n] =                                                              \
            __builtin_amdgcn_mfma_f32_16x16x32_bf16(af[m], bfv[n], acc[m][n], 0, 0, 0); \
    asm volatile("s_waitcnt vmcnt(" #VM ")" ::: "memory");                       \
    __builtin_amdgcn_s_barrier();                                                \
  }

  {
    int c0 = 0;
    for (int kt = 0; kt < nk - 2; ++kt) {
      const int c2 = (c0 >= 1) ? (c0 - 1) : (c0 + 2);  // (c0+2)%3
      QTILE(kt, c0, c2, 1, 4);
      c0 = (c0 >= 2) ? 0 : (c0 + 1);
    }
    QTILE(nk - 2, c0, 0, 0, 0);
    c0 = (c0 >= 2) ? 0 : (c0 + 1);
    QTILE(nk - 1, c0, 0, 0, 0);
  }
#undef QTILE

  if (tn >= 16) {
    unsigned short* q16 = (unsigned short*)Cp;
#pragma unroll
    for (int m = 0; m < 8; ++m)
#pragma unroll
      for (int n = 0; n < 4; ++n) {
        int row = tm * 256 + wr * 128 + m * 16 + lk * 4;
        int b_ = row >> 11, t0 = row & 2047;
        int c = tn * 256 - 4096 + wc * 64 + n * 16 + lq;
        ushort4 o;
        o.x = f2bf(acc[m][n][0]); o.y = f2bf(acc[m][n][1]);
        o.z = f2bf(acc[m][n][2]); o.w = f2bf(acc[m][n][3]);
        *(ushort4*)(q16 + (size_t)(b_ * 2048 + c) * N1 + 4096 + t0) = o;
      }
  } else {
#pragma unroll
    for (int m = 0; m < 8; ++m)
#pragma unroll
      for (int n = 0; n < 4; ++n)
#pragma unroll
        for (int r2 = 0; r2 < 4; ++r2) {
          int row = tm * 256 + wr * 128 + m * 16 + lk * 4 + r2;
          int col = tn * 256 + wc * 64 + n * 16 + lq;
          ((unsigned short*)Cp)[(size_t)row * Nn + col] = f2bf(acc[m][n][r2]);
        }
  }
}

// ---------------- gemm_p: 128x256 ring-3, 2-barrier body (proj GEMM, R8 exact) ----------------
__global__ __launch_bounds__(512, 4) void gemm_p(const bf16_t* __restrict__ A,
                                                 const bf16_t* __restrict__ BT,
                                                 float* __restrict__ Cp,
                                                 int Nn, int Kk) {
  constexpr int SLOT = 24576;
  __shared__ __align__(16) char ldsmem[3 * SLOT];
  char* ldsb = ldsmem;

  const int tid = threadIdx.x;
  const int wid = tid >> 6, lane = tid & 63;
  const int lq = lane & 15, lk = lane >> 4;
  const int wr = wid >> 2, wc = wid & 3;

  const int bid = blockIdx.x;
  const int xcd = bid & 7;
  const int j = bid >> 3;
  const int r = j & 31, s5 = j >> 5;
  const int tn = s5 * 8 + (r & 7);
  const int tm = xcd * 4 + (r >> 3);

  f32x4 acc[4][4] = {};

  int aoff[4], boff[4];
#pragma unroll
  for (int m = 0; m < 4; ++m) {
    int row = wr * 64 + m * 16 + lq;
    aoff[m] = row * 64 + ((lk * 16) ^ (((row >> 1) & 3) << 4));
  }
#pragma unroll
  for (int n = 0; n < 4; ++n) {
    int brow = wc * 64 + n * 16 + lq;
    boff[n] = 8192 + brow * 64 + ((lk * 16) ^ (((brow >> 1) & 3) << 4));
  }

  const int pA = wid * 1024 + lane * 16;
  const int arow = pA >> 6;
  const int acsw = (pA & 63) ^ (((arow >> 1) & 3) << 4);
  const bf16_t* Ags = A + (size_t)(tm * 128 + arow) * Kk + (acsw >> 1);

  const int pB0 = wid * 1024 + lane * 16;
  const int brow0 = pB0 >> 6;
  const int bcsw0 = (pB0 & 63) ^ (((brow0 >> 1) & 3) << 4);
  const bf16_t* Bgs0 = BT + (size_t)(tn * 256 + brow0) * Kk + (bcsw0 >> 1);

  const int pB1 = 8192 + wid * 1024 + lane * 16;
  const int brow1 = pB1 >> 6;  // 128..255
  const int bcsw1 = (pB1 & 63) ^ (((brow1 >> 1) & 3) << 4);
  const bf16_t* Bgs1 = BT + (size_t)(tn * 256 + brow1) * Kk + (bcsw1 >> 1);

  const int ldsA = wid * 1024;
  const int ldsB0 = 8192 + wid * 1024;
  const int ldsB1 = 16384 + wid * 1024;

  auto stage = [&](int kt, int slot) {
    char* db = ldsb + slot * SLOT;
    gload_lds16(Ags + (size_t)kt * 32, db + ldsA);
    gload_lds16(Bgs0 + (size_t)kt * 32, db + ldsB0);
    gload_lds16(Bgs1 + (size_t)kt * 32, db + ldsB1);
  };

  const int nk = Kk >> 5;

  stage(0, 0); stage(1, 1);
  asm volatile("s_waitcnt vmcnt(3)" ::: "memory");
  __builtin_amdgcn_s_barrier();

#define TILE_BODY(KT, SLOT0, SLOT2, STAGE_EN, VM)                                \
  {                                                                              \
    __builtin_amdgcn_sched_barrier(0);                                           \
    const char* sb = ldsb + (SLOT0) * SLOT;                                      \
    bf16x8 af[4], bfv[4];                                                        \
    _Pragma("unroll") for (int m = 0; m < 4; ++m)                                \
      af[m] = *(const bf16x8*)(sb + aoff[m]);                                    \
    _Pragma("unroll") for (int n = 0; n < 4; ++n)                                \
      bfv[n] = *(const bf16x8*)(sb + boff[n]);                                   \
    if (STAGE_EN) stage((KT) + 2, (SLOT2));                                      \
    __builtin_amdgcn_sched_barrier(0);                                           \
    __builtin_amdgcn_s_barrier();                                                \
    asm volatile("s_waitcnt lgkmcnt(0)" ::: "memory");                           \
    __builtin_amdgcn_sched_barrier(0);                                           \
    __builtin_amdgcn_s_setprio(1);                                               \
    _Pragma("unroll") for (int m = 0; m < 4; ++m)                                \
      _Pragma("unroll") for (int n = 0; n < 4; ++n)                              \
        acc[m][n] =                                                              \
            __builtin_amdgcn_mfma_f32_16x16x32_bf16(af[m], bfv[n], acc[m][n], 0, 0, 0); \
    __builtin_amdgcn_s_setprio(0);                                               \
    __builtin_amdgcn_sched_barrier(0);                                           \
    asm volatile("s_waitcnt vmcnt(" #VM ")" ::: "memory");                       \
    __builtin_amdgcn_s_barrier();                                                \
  }

  {
    int c0 = 0;
    for (int kt = 0; kt < nk - 2; ++kt) {
      const int c2 = (c0 >= 1) ? (c0 - 1) : (c0 + 2);
      TILE_BODY(kt, c0, c2, 1, 3);
      c0 = (c0 >= 2) ? 0 : (c0 + 1);
    }
    TILE_BODY(nk - 2, c0, 0, 0, 0);
    c0 = (c0 >= 2) ? 0 : (c0 + 1);
    TILE_BODY(nk - 1, c0, 0, 0, 0);
  }
#undef TILE_BODY

#pragma unroll
  for (int m = 0; m < 4; ++m)
#pragma unroll
    for (int n = 0; n < 4; ++n)
#pragma unroll
      for (int r2 = 0; r2 < 4; ++r2) {
        int row = tm * 128 + wr * 64 + m * 16 + lk * 4 + r2;
        int col = tn * 256 + wc * 64 + n * 16 + lq;
        Cp[(size_t)row * Nn + col] = acc[m][n][r2];
      }
}

// ---------------- causal flash attention (unchanged) ----------------
__global__ __launch_bounds__(512, 1) void attn_kernel(const bf16_t* __restrict__ qkv,
                                                      unsigned short* __restrict__ y) {
  __shared__ __align__(16) char lds[98304];  // 3 slots x (K 16KB + V 16KB)
  const int tid = threadIdx.x;
  const int wid = tid >> 6, lane = tid & 63;
  const int l31 = lane & 31, hi = lane >> 5;
  const int hi16 = hi << 4;
  const int bh = blockIdx.x;
  const int g = blockIdx.y;
  const int b = bh >> 4, h = bh & 15;
  const float SC2 = 0.12751879868954096f;  // (1/sqrt(128)) * log2(e)

  const int grp = (wid < 4) ? g : (15 - g);
  const int qlo = grp * 128 + (wid & 3) * 32;
  const int qidx = qlo + l31;
  const int nt = 2 * (15 - g) + 2;
  const size_t rowbase = (size_t)(b * T) * N1;

  bf16x8 qf[8];
  {
    const bf16_t* Qg = qkv + rowbase + (size_t)qidx * N1 + h * DH + hi * 8;
#pragma unroll
    for (int kk = 0; kk < 8; ++kk) qf[kk] = *(const bf16x8*)(Qg + kk * 16);
  }

  const bf16_t* Kg0 = qkv + rowbase + Cdim + h * DH;
  const bf16_t* Vg0 = qkv + (size_t)(b * 2048 + h * DH) * N1 + 2 * Cdim;
  const int p0 = wid * 1024 + lane * 16;
  const int p1 = 8192 + wid * 1024 + lane * 16;
  const int kr0 = p0 >> 8, kr1 = p1 >> 8;
  const bf16_t* KsA = Kg0 + (size_t)kr0 * N1 + ((((p0 & 255) ^ ((kr0 & 15) << 4))) >> 1);
  const bf16_t* KsB = Kg0 + (size_t)kr1 * N1 + ((((p1 & 255) ^ ((kr1 & 15) << 4))) >> 1);
  const int vr0 = p0 >> 7, vr1 = p1 >> 7;
  const bf16_t* VsA = Vg0 + (size_t)vr0 * N1 + ((((p0 & 127) ^ ((vr0 & 7) << 4))) >> 1);
  const bf16_t* VsB = Vg0 + (size_t)vr1 * N1 + ((((p1 & 127) ^ ((vr1 & 7) << 4))) >> 1);
  const int dstoff = wid * 1024;

  auto stage = [&](int tt, int slot) {
    char* Kd = lds + slot * 32768;
    char* Vd = Kd + 16384;
    const size_t ko = (size_t)(tt * 64) * N1;
    const int vo = tt * 64;
    gload_lds16(KsA + ko, Kd + dstoff);
    gload_lds16(KsB + ko, Kd + 8192 + dstoff);
    gload_lds16(VsA + vo, Vd + dstoff);
    gload_lds16(VsB + vo, Vd + 8192 + dstoff);
  };

  f32x16 oacc[4] = {};
  float mrow = -1e30f, lrow = 0.f;

  stage(0, 0); stage(1, 1);
  asm volatile("s_waitcnt vmcnt(4)" ::: "memory");
  __builtin_amdgcn_s_barrier();

  int cs = 0;
  for (int t = 0; t < nt; ++t) {
    const int kv0 = t * 64;
    if (t + 2 < nt) {
      const int s2 = (cs >= 1) ? (cs - 1) : (cs + 2);
      stage(t + 2, s2);
    }

    if (kv0 <= qlo + 31) {
      f32x16 s0 = {}, s1 = {};
      {
        const char* Kb = lds + cs * 32768;
        const char* krow0 = Kb + l31 * 256;
        const char* krow1 = Kb + (32 + l31) * 256;
        const int sw0 = (l31 & 15) << 4;
#pragma unroll
        for (int kk = 0; kk < 8; ++kk) {
          bf16x8 kf0 = *(const bf16x8*)(krow0 + ((kk * 32 + hi16) ^ sw0));
          bf16x8 kf1 = *(const bf16x8*)(krow1 + ((kk * 32 + hi16) ^ sw0));
          s0 = __builtin_amdgcn_mfma_f32_32x32x16_bf16(kf0, qf[kk], s0, 0, 0, 0);
          s1 = __builtin_amdgcn_mfma_f32_32x32x16_bf16(kf1, qf[kk], s1, 0, 0, 0);
        }
      }
      float sv[32];
#pragma unroll
      for (int r = 0; r < 16; ++r) { sv[r] = s0[r]; sv[16 + r] = s1[r]; }
      if (kv0 + 63 > qlo) {
#pragma unroll
        for (int r = 0; r < 16; ++r) {
          const int roff = (r & 3) + 8 * (r >> 2);
          if (kv0 + roff + 4 * hi > qidx) sv[r] = -1e30f;
          if (kv0 + 32 + roff + 4 * hi > qidx) sv[16 + r] = -1e30f;
        }
      }
      float mx = sv[0];
#pragma unroll
      for (int i = 1; i < 32; ++i) mx = fmaxf(mx, sv[i]);
      mx = fmaxf(mx, __shfl_xor(mx, 32));
      const float mn = fmaxf(mrow, mx);
      const float osc = ex2((mrow - mn) * SC2);
      mrow = mn;
      const float mn2 = mn * SC2;
#pragma unroll
      for (int db = 0; db < 4; ++db) oacc[db] *= osc;
      float srow = 0.f;
#pragma unroll
      for (int i = 0; i < 32; ++i) {
        float p = ex2(fmaf(sv[i], SC2, -mn2));
        sv[i] = p;
        srow += p;
      }
      srow += __shfl_xor(srow, 32);
      lrow = lrow * osc + srow;
      bf16x8 pb[4];
#pragma unroll
      for (int s4 = 0; s4 < 4; ++s4) {
        const int base = (s4 >> 1) * 16 + (s4 & 1) * 8;
        unsigned x0 = pk2(sv[base + 0], sv[base + 1]);
        unsigned x1 = pk2(sv[base + 2], sv[base + 3]);
        unsigned y0 = pk2(sv[base + 4], sv[base + 5]);
        unsigned y1 = pk2(sv[base + 6], sv[base + 7]);
        unsigned e0 = (unsigned)__shfl_xor((int)(hi ? x0 : y0), 32);
        unsigned e1 = (unsigned)__shfl_xor((int)(hi ? x1 : y1), 32);
        union { unsigned u[4]; bf16x8 v; } pbu;
        pbu.u[0] = hi ? e0 : x0;
        pbu.u[1] = hi ? e1 : x1;
        pbu.u[2] = hi ? y0 : e0;
        pbu.u[3] = hi ? y1 : e1;
        pb[s4] = pbu.v;
      }
      {
        const char* Vb = lds + cs * 32768 + 16384;
#pragma unroll
        for (int db = 0; db < 4; ++db) {
          const int vrow = db * 32 + l31;
          const char* vr = Vb + vrow * 128;
          const int swv = (vrow & 7) << 4;
#pragma unroll
          for (int s4 = 0; s4 < 4; ++s4) {
            bf16x8 vf = *(const bf16x8*)(vr + ((s4 * 32 + hi16) ^ swv));
            oacc[db] = __builtin_amdgcn_mfma_f32_32x32x16_bf16(vf, pb[s4], oacc[db], 0, 0, 0);
          }
        }
      }
    }

    asm volatile("s_waitcnt vmcnt(4)" ::: "memory");
    __builtin_amdgcn_s_barrier();
    cs = (cs >= 2) ? 0 : (cs + 1);
  }

  const float inv = 1.0f / lrow;
  char* eb = lds + wid * 8192;
#pragma unroll
  for (int db = 0; db < 4; ++db)
#pragma unroll
    for (int r = 0; r < 16; ++r) {
      const int d = db * 32 + (r & 3) + 8 * (r >> 2) + 4 * hi;
      const int off = l31 * 256 + ((d * 2) ^ ((l31 & 15) << 4));
      *(unsigned short*)(eb + off) = f2bf(oacc[db][r] * inv);
    }
  asm volatile("s_waitcnt lgkmcnt(0)" ::: "memory");
  __builtin_amdgcn_sched_barrier(0);
  {
    unsigned short* yr = y + (size_t)(b * T + qlo + l31) * Cdim + h * DH;
#pragma unroll
    for (int rr = 0; rr < 8; ++rr) {
      const int c = hi * 8 + rr;
      bf16x8 v = *(const bf16x8*)(eb + l31 * 256 + ((c * 16) ^ ((l31 & 15) << 4)));
      *(bf16x8*)(yr + c * 8) = v;
    }
  }
}

extern "C" void kernel_launch(void* const* d_in, const int* in_sizes, int n_in,
                              void* d_out, int out_size, void* d_ws, size_t ws_size,
                              hipStream_t stream) {
  const float* x  = (const float*)d_in[0];
  const float* Wa = (const float*)d_in[1];
  const float* Wp = (const float*)d_in[2];
  float* out = (float*)d_out;
  char* ws = (char*)d_ws;

  size_t o0 = 0;                            // xb : M*K1 bf16
  size_t o1 = o0 + (size_t)M * K1 * 2;      // WaT: N1*K1 bf16
  size_t o2 = o1 + (size_t)N1 * K1 * 2;     // qkv: M*N1 bf16 (V stripe holds Vt remap)
  size_t o3 = o2 + (size_t)M * N1 * 2;      // yb : M*C bf16
  size_t o4 = o3 + (size_t)M * Cdim * 2;    // WpT: C*C bf16

  unsigned short* xb   = (unsigned short*)(ws + o0);
  unsigned short* WaT  = (unsigned short*)(ws + o1);
  unsigned short* qkvb = (unsigned short*)(ws + o2);
  unsigned short* yb   = (unsigned short*)(ws + o3);
  unsigned short* WpT  = (unsigned short*)(ws + o4);

  // blocks: 8192 cvt + 6144 Wa^T (32 k-bands x 192 n-tiles) + 2048 Wp^T
  preamble_kernel<<<dim3(16384), dim3(256), 0, stream>>>(x, Wa, Wp, xb, WaT, WpT);

  // qkv GEMM: 256x256 tiles ring-3, grid = 16*24 = 384 blocks
  gemm_q<<<dim3((M / 256) * (N1 / 256)), dim3(512), 0, stream>>>(
      (const bf16_t*)xb, (const bf16_t*)WaT, (void*)qkvb, N1, K1);

  attn_kernel<<<dim3(Bsz * NH, 8), dim3(512), 0, stream>>>(
      (const bf16_t*)qkvb, yb);

  // proj GEMM: 128x256 tiles, grid = 32*8 = 256 blocks
  gemm_p<<<dim3((M / 128) * (Cdim / 256)), dim3(512), 0, stream>>>(
      (const bf16_t*)yb, (const bf16_t*)WpT, out, Cdim, K1);
}

// Round 14
// 233.147 us; speedup vs baseline: 1.0491x; 1.0230x over previous
//
#include <hip/hip_runtime.h>
#include <hip/hip_bf16.h>
#include <stdint.h>

#define AS1 __attribute__((address_space(1)))
#define AS3 __attribute__((address_space(3)))

typedef __bf16 bf16_t;
typedef __bf16 bf16x8 __attribute__((ext_vector_type(8)));
typedef float f32x4 __attribute__((ext_vector_type(4)));
typedef float f32x16 __attribute__((ext_vector_type(16)));

static constexpr int Bsz = 2, T = 2048, Cdim = 2048, NH = 16, DH = 128;
static constexpr int M  = Bsz * T;    // 4096
static constexpr int N1 = 3 * Cdim;   // 6144
static constexpr int K1 = Cdim;       // 2048

__device__ __forceinline__ unsigned short f2bf(float f) {
  unsigned u = __float_as_uint(f);
  u += 0x7fffu + ((u >> 16) & 1u);
  return (unsigned short)(u >> 16);
}

__device__ __forceinline__ void gload_lds16(const bf16_t* g, void* l) {
  __builtin_amdgcn_global_load_lds((AS1 const void*)g, (AS3 void*)l, 16, 0, 0);
}

__device__ __forceinline__ float ex2(float x) {
  float r; asm("v_exp_f32 %0, %1" : "=v"(r) : "v"(x)); return r;
}
__device__ __forceinline__ unsigned pk2(float a, float b) {
  unsigned r; asm("v_cvt_pk_bf16_f32 %0, %1, %2" : "=v"(r) : "v"(a), "v"(b)); return r;
}

// ---------------- fused preamble: cvt(x) + transpose(Wa) + transpose(Wp) ----------------
__global__ __launch_bounds__(256) void preamble_kernel(const float* __restrict__ x,
                                                       const float* __restrict__ Wa,
                                                       const float* __restrict__ Wp,
                                                       unsigned short* __restrict__ xb,
                                                       unsigned short* __restrict__ WaT,
                                                       unsigned short* __restrict__ WpT) {
  __shared__ float tile[32][33];
  const int blk = blockIdx.x;
  const int tid = threadIdx.x;
  if (blk < 8192) {
    int i = blk * 1024 + tid * 4;
    float4 v = *(const float4*)(x + i);
    ushort4 o;
    o.x = f2bf(v.x); o.y = f2bf(v.y); o.z = f2bf(v.z); o.w = f2bf(v.w);
    *(ushort4*)(xb + i) = o;
    return;
  }
  const float* in;
  unsigned short* out;
  int Nn, bi;
  if (blk < 20480) { in = Wa; out = WaT; Nn = N1;   bi = blk - 8192;  }
  else             { in = Wp; out = WpT; Nn = Cdim; bi = blk - 20480; }
  const int ntiles = Nn >> 5;
  const int n0 = (bi % ntiles) * 32, k0 = (bi / ntiles) * 32;
  const int tx = tid & 31, ty = tid >> 5;  // 32 x 8
#pragma unroll
  for (int i = 0; i < 32; i += 8)
    tile[ty + i][tx] = in[(size_t)(k0 + ty + i) * Nn + n0 + tx];
  __syncthreads();
#pragma unroll
  for (int i = 0; i < 32; i += 8)
    out[(size_t)(n0 + ty + i) * K1 + k0 + tx] = f2bf(tile[tx][ty + i]);
}

// ---------------- deep-pipelined bf16 GEMM: A (MxK) * BT (NxK) ----------------
// BM=128, BN=256, BK=32. 8 waves (2M x 4N), per-wave 64x64 output.
// Ring-3 LDS (72 KiB, 2 blocks/CU), prefetch 2 K-tiles ahead, counted vmcnt(3),
// raw s_barrier, setprio around MFMA, XOR-swizzled LDS.
// L2-aware XCD mapping: XCD = bid%8 owns tm in [xcd*4, xcd*4+4), walks tn in
// 8-wide chunks -> per-XCD window: A 2 MB pinned + B 8 MB.
// MODE 0: fp32 out. MODE 1: qkv bf16 out; V-region (tn>=16) written transposed
// into the qkv V stripe remapped as (b*2048+c)*6144 + 4096 + t.
template <int MODE>
__global__ __launch_bounds__(512, 4) void gemm_p3(const bf16_t* __restrict__ A,
                                                  const bf16_t* __restrict__ BT,
                                                  void* __restrict__ Cp,
                                                  int Nn, int Kk) {
  constexpr int SLOT = 24576;
  __shared__ __align__(16) char ldsmem[3 * SLOT];
  char* ldsb = ldsmem;

  const int tid = threadIdx.x;
  const int wid = tid >> 6, lane = tid & 63;
  const int lq = lane & 15, lk = lane >> 4;
  const int wr = wid >> 2, wc = wid & 3;

  // L2-aware XCD mapping (gy=32, gx%8==0)
  const int bid = blockIdx.x;
  const int xcd = bid & 7;
  const int j = bid >> 3;
  const int r = j & 31, s5 = j >> 5;
  const int tn = s5 * 8 + (r & 7);
  const int tm = xcd * 4 + (r >> 3);

  f32x4 acc[4][4] = {};

  int aoff[4], boff[4];
#pragma unroll
  for (int m = 0; m < 4; ++m) {
    int row = wr * 64 + m * 16 + lq;
    aoff[m] = row * 64 + ((lk * 16) ^ (((row >> 1) & 3) << 4));
  }
#pragma unroll
  for (int n = 0; n < 4; ++n) {
    int brow = wc * 64 + n * 16 + lq;
    boff[n] = 8192 + brow * 64 + ((lk * 16) ^ (((brow >> 1) & 3) << 4));
  }

  const int pA = wid * 1024 + lane * 16;
  const int arow = pA >> 6;
  const int acsw = (pA & 63) ^ (((arow >> 1) & 3) << 4);
  const bf16_t* Ags = A + (size_t)(tm * 128 + arow) * Kk + (acsw >> 1);

  const int pB0 = wid * 1024 + lane * 16;
  const int brow0 = pB0 >> 6;
  const int bcsw0 = (pB0 & 63) ^ (((brow0 >> 1) & 3) << 4);
  const bf16_t* Bgs0 = BT + (size_t)(tn * 256 + brow0) * Kk + (bcsw0 >> 1);

  const int pB1 = 8192 + wid * 1024 + lane * 16;
  const int brow1 = pB1 >> 6;  // 128..255
  const int bcsw1 = (pB1 & 63) ^ (((brow1 >> 1) & 3) << 4);
  const bf16_t* Bgs1 = BT + (size_t)(tn * 256 + brow1) * Kk + (bcsw1 >> 1);

  const int ldsA = wid * 1024;
  const int ldsB0 = 8192 + wid * 1024;
  const int ldsB1 = 16384 + wid * 1024;

  auto stage = [&](int kt, int slot) {
    char* db = ldsb + slot * SLOT;
    gload_lds16(Ags + (size_t)kt * 32, db + ldsA);
    gload_lds16(Bgs0 + (size_t)kt * 32, db + ldsB0);
    gload_lds16(Bgs1 + (size_t)kt * 32, db + ldsB1);
  };

  const int nk = Kk >> 5;

  stage(0, 0); stage(1, 1);
  asm volatile("s_waitcnt vmcnt(3)" ::: "memory");
  __builtin_amdgcn_s_barrier();

#define TILE_BODY(KT, SLOT0, SLOT2, STAGE_EN, VM)                                \
  {                                                                              \
    __builtin_amdgcn_sched_barrier(0);                                           \
    const char* sb = ldsb + (SLOT0) * SLOT;                                      \
    bf16x8 af[4], bfv[4];                                                        \
    _Pragma("unroll") for (int m = 0; m < 4; ++m)                                \
      af[m] = *(const bf16x8*)(sb + aoff[m]);                                    \
    _Pragma("unroll") for (int n = 0; n < 4; ++n)                                \
      bfv[n] = *(const bf16x8*)(sb + boff[n]);                                   \
    if (STAGE_EN) stage((KT) + 2, (SLOT2));                                      \
    __builtin_amdgcn_sched_barrier(0);                                           \
    __builtin_amdgcn_s_barrier();                                                \
    asm volatile("s_waitcnt lgkmcnt(0)" ::: "memory");                           \
    __builtin_amdgcn_sched_barrier(0);                                           \
    __builtin_amdgcn_s_setprio(1);                                               \
    _Pragma("unroll") for (int m = 0; m < 4; ++m)                                \
      _Pragma("unroll") for (int n = 0; n < 4; ++n)                              \
        acc[m][n] =                                                              \
            __builtin_amdgcn_mfma_f32_16x16x32_bf16(af[m], bfv[n], acc[m][n], 0, 0, 0); \
    __builtin_amdgcn_s_setprio(0);                                               \
    __builtin_amdgcn_sched_barrier(0);                                           \
    asm volatile("s_waitcnt vmcnt(" #VM ")" ::: "memory");                       \
    __builtin_amdgcn_s_barrier();                                                \
  }

  {
    int c0 = 0;  // slot of tile kt
    for (int kt = 0; kt < nk - 2; ++kt) {
      const int c2 = (c0 >= 1) ? (c0 - 1) : (c0 + 2);  // (c0+2)%3
      TILE_BODY(kt, c0, c2, 1, 3);
      c0 = (c0 >= 2) ? 0 : (c0 + 1);
    }
    TILE_BODY(nk - 2, c0, 0, 0, 0);
    c0 = (c0 >= 2) ? 0 : (c0 + 1);
    TILE_BODY(nk - 1, c0, 0, 0, 0);
  }
#undef TILE_BODY

  if (MODE == 1 && tn >= 16) {
    // V region: write transposed into qkv V stripe: (b*2048+c)*6144 + 4096 + t
    unsigned short* q16 = (unsigned short*)Cp;
#pragma unroll
    for (int m = 0; m < 4; ++m)
#pragma unroll
      for (int n = 0; n < 4; ++n) {
        int row = tm * 128 + wr * 64 + m * 16 + lk * 4;
        int b_ = row >> 11, t0 = row & 2047;
        int c = tn * 256 - 4096 + wc * 64 + n * 16 + lq;
        ushort4 o;
        o.x = f2bf(acc[m][n][0]); o.y = f2bf(acc[m][n][1]);
        o.z = f2bf(acc[m][n][2]); o.w = f2bf(acc[m][n][3]);
        *(ushort4*)(q16 + (size_t)(b_ * 2048 + c) * N1 + 4096 + t0) = o;
      }
  } else {
#pragma unroll
    for (int m = 0; m < 4; ++m)
#pragma unroll
      for (int n = 0; n < 4; ++n)
#pragma unroll
        for (int r2 = 0; r2 < 4; ++r2) {
          int row = tm * 128 + wr * 64 + m * 16 + lk * 4 + r2;
          int col = tn * 256 + wc * 64 + n * 16 + lq;
          if (MODE == 1)
            ((unsigned short*)Cp)[(size_t)row * Nn + col] = f2bf(acc[m][n][r2]);
          else
            ((float*)Cp)[(size_t)row * Nn + col] = acc[m][n][r2];
        }
  }
}

// ---------------- causal flash attention: swapped-QK^T 32x32, 8 waves ----------------
// Waves 0-3: q-group g; waves 4-7: q-group 15-g (balanced pairing).
// S^T = mfma(K, Q): q = lane&31 lane-local. O^T = mfma(V^T, P^T). P in registers.
// Ring-3 K/V staging (3 x 32KB), prefetch 2 tiles ahead, counted vmcnt(4).
__global__ __launch_bounds__(512, 1) void attn_kernel(const bf16_t* __restrict__ qkv,
                                                      unsigned short* __restrict__ y) {
  __shared__ __align__(16) char lds[98304];  // 3 slots x (K 16KB + V 16KB)
  const int tid = threadIdx.x;
  const int wid = tid >> 6, lane = tid & 63;
  const int l31 = lane & 31, hi = lane >> 5;
  const int hi16 = hi << 4;
  const int bh = blockIdx.x;
  const int g = blockIdx.y;              // pair index 0..7
  const int b = bh >> 4, h = bh & 15;
  const float SC2 = 0.12751879868954096f;  // (1/sqrt(128)) * log2(e)

  const int grp = (wid < 4) ? g : (15 - g);
  const int qlo = grp * 128 + (wid & 3) * 32;
  const int qidx = qlo + l31;
  const int nt = 2 * (15 - g) + 2;
  const size_t rowbase = (size_t)(b * T) * N1;

  // Q fragments: qf[kk] elem j = Q[qlo+l31][16kk + 8hi + j]
  bf16x8 qf[8];
  {
    const bf16_t* Qg = qkv + rowbase + (size_t)qidx * N1 + h * DH + hi * 8;
#pragma unroll
    for (int kk = 0; kk < 8; ++kk) qf[kk] = *(const bf16x8*)(Qg + kk * 16);
  }

  // staging source pointers (inverse-swizzled global, linear LDS dest)
  const bf16_t* Kg0 = qkv + rowbase + Cdim + h * DH;
  const bf16_t* Vg0 = qkv + (size_t)(b * 2048 + h * DH) * N1 + 2 * Cdim;
  const int p0 = wid * 1024 + lane * 16;
  const int p1 = 8192 + wid * 1024 + lane * 16;
  const int kr0 = p0 >> 8, kr1 = p1 >> 8;
  const bf16_t* KsA = Kg0 + (size_t)kr0 * N1 + ((((p0 & 255) ^ ((kr0 & 15) << 4))) >> 1);
  const bf16_t* KsB = Kg0 + (size_t)kr1 * N1 + ((((p1 & 255) ^ ((kr1 & 15) << 4))) >> 1);
  const int vr0 = p0 >> 7, vr1 = p1 >> 7;
  const bf16_t* VsA = Vg0 + (size_t)vr0 * N1 + ((((p0 & 127) ^ ((vr0 & 7) << 4))) >> 1);
  const bf16_t* VsB = Vg0 + (size_t)vr1 * N1 + ((((p1 & 127) ^ ((vr1 & 7) << 4))) >> 1);
  const int dstoff = wid * 1024;

  auto stage = [&](int tt, int slot) {
    char* Kd = lds + slot * 32768;
    char* Vd = Kd + 16384;
    const size_t ko = (size_t)(tt * 64) * N1;
    const int vo = tt * 64;
    gload_lds16(KsA + ko, Kd + dstoff);
    gload_lds16(KsB + ko, Kd + 8192 + dstoff);
    gload_lds16(VsA + vo, Vd + dstoff);
    gload_lds16(VsB + vo, Vd + 8192 + dstoff);
  };

  f32x16 oacc[4] = {};
  float mrow = -1e30f, lrow = 0.f;

  stage(0, 0); stage(1, 1);
  asm volatile("s_waitcnt vmcnt(4)" ::: "memory");
  __builtin_amdgcn_s_barrier();

  int cs = 0;
  for (int t = 0; t < nt; ++t) {
    const int kv0 = t * 64;
    if (t + 2 < nt) {
      const int s2 = (cs >= 1) ? (cs - 1) : (cs + 2);  // (cs+2)%3
      stage(t + 2, s2);
    }

    if (kv0 <= qlo + 31) {
      // ---- S^T = K Q^T ----
      f32x16 s0 = {}, s1 = {};
      {
        const char* Kb = lds + cs * 32768;
        const char* krow0 = Kb + l31 * 256;
        const char* krow1 = Kb + (32 + l31) * 256;
        const int sw0 = (l31 & 15) << 4;
#pragma unroll
        for (int kk = 0; kk < 8; ++kk) {
          bf16x8 kf0 = *(const bf16x8*)(krow0 + ((kk * 32 + hi16) ^ sw0));
          bf16x8 kf1 = *(const bf16x8*)(krow1 + ((kk * 32 + hi16) ^ sw0));
          s0 = __builtin_amdgcn_mfma_f32_32x32x16_bf16(kf0, qf[kk], s0, 0, 0, 0);
          s1 = __builtin_amdgcn_mfma_f32_32x32x16_bf16(kf1, qf[kk], s1, 0, 0, 0);
        }
      }
      float sv[32];
#pragma unroll
      for (int r = 0; r < 16; ++r) { sv[r] = s0[r]; sv[16 + r] = s1[r]; }
      if (kv0 + 63 > qlo) {  // (partially) diagonal tile: causal mask
#pragma unroll
        for (int r = 0; r < 16; ++r) {
          const int roff = (r & 3) + 8 * (r >> 2);
          if (kv0 + roff + 4 * hi > qidx) sv[r] = -1e30f;
          if (kv0 + 32 + roff + 4 * hi > qidx) sv[16 + r] = -1e30f;
        }
      }
      // ---- online softmax (q lane-local) ----
      float mx = sv[0];
#pragma unroll
      for (int i = 1; i < 32; ++i) mx = fmaxf(mx, sv[i]);
      mx = fmaxf(mx, __shfl_xor(mx, 32));
      const float mn = fmaxf(mrow, mx);
      const float osc = ex2((mrow - mn) * SC2);
      mrow = mn;
      const float mn2 = mn * SC2;
#pragma unroll
      for (int db = 0; db < 4; ++db) oacc[db] *= osc;
      float srow = 0.f;
#pragma unroll
      for (int i = 0; i < 32; ++i) {
        float p = ex2(fmaf(sv[i], SC2, -mn2));
        sv[i] = p;
        srow += p;
      }
      srow += __shfl_xor(srow, 32);
      lrow = lrow * osc + srow;
      // ---- build P^T B-fragments in-register (cvt_pk + lane^32 exchange) ----
      bf16x8 pb[4];
#pragma unroll
      for (int s4 = 0; s4 < 4; ++s4) {
        const int base = (s4 >> 1) * 16 + (s4 & 1) * 8;
        unsigned x0 = pk2(sv[base + 0], sv[base + 1]);
        unsigned x1 = pk2(sv[base + 2], sv[base + 3]);
        unsigned y0 = pk2(sv[base + 4], sv[base + 5]);
        unsigned y1 = pk2(sv[base + 6], sv[base + 7]);
        unsigned e0 = (unsigned)__shfl_xor((int)(hi ? x0 : y0), 32);
        unsigned e1 = (unsigned)__shfl_xor((int)(hi ? x1 : y1), 32);
        union { unsigned u[4]; bf16x8 v; } pbu;
        pbu.u[0] = hi ? e0 : x0;
        pbu.u[1] = hi ? e1 : x1;
        pbu.u[2] = hi ? y0 : e0;
        pbu.u[3] = hi ? y1 : e1;
        pb[s4] = pbu.v;
      }
      // ---- O^T += V^T P^T ----
      {
        const char* Vb = lds + cs * 32768 + 16384;
#pragma unroll
        for (int db = 0; db < 4; ++db) {
          const int vrow = db * 32 + l31;
          const char* vr = Vb + vrow * 128;
          const int swv = (vrow & 7) << 4;
#pragma unroll
          for (int s4 = 0; s4 < 4; ++s4) {
            bf16x8 vf = *(const bf16x8*)(vr + ((s4 * 32 + hi16) ^ swv));
            oacc[db] = __builtin_amdgcn_mfma_f32_32x32x16_bf16(vf, pb[s4], oacc[db], 0, 0, 0);
          }
        }
      }
    }

    asm volatile("s_waitcnt vmcnt(4)" ::: "memory");
    __builtin_amdgcn_s_barrier();
    cs = (cs >= 2) ? 0 : (cs + 1);
  }

  // ---- epilogue: O^T[d][q] -> y[q][d] via per-wave LDS transpose ----
  const float inv = 1.0f / lrow;
  char* eb = lds + wid * 8192;  // 32 rows x 256 B, swizzled (per-wave private)
#pragma unroll
  for (int db = 0; db < 4; ++db)
#pragma unroll
    for (int r = 0; r < 16; ++r) {
      const int d = db * 32 + (r & 3) + 8 * (r >> 2) + 4 * hi;
      const int off = l31 * 256 + ((d * 2) ^ ((l31 & 15) << 4));
      *(unsigned short*)(eb + off) = f2bf(oacc[db][r] * inv);
    }
  asm volatile("s_waitcnt lgkmcnt(0)" ::: "memory");
  __builtin_amdgcn_sched_barrier(0);
  {
    unsigned short* yr = y + (size_t)(b * T + qlo + l31) * Cdim + h * DH;
#pragma unroll
    for (int rr = 0; rr < 8; ++rr) {
      const int c = hi * 8 + rr;  // 0..15 -> d = c*8 .. c*8+7 (full 128)
      bf16x8 v = *(const bf16x8*)(eb + l31 * 256 + ((c * 16) ^ ((l31 & 15) << 4)));
      *(bf16x8*)(yr + c * 8) = v;
    }
  }
}

extern "C" void kernel_launch(void* const* d_in, const int* in_sizes, int n_in,
                              void* d_out, int out_size, void* d_ws, size_t ws_size,
                              hipStream_t stream) {
  const float* x  = (const float*)d_in[0];
  const float* Wa = (const float*)d_in[1];
  const float* Wp = (const float*)d_in[2];
  float* out = (float*)d_out;
  char* ws = (char*)d_ws;

  size_t o0 = 0;                            // xb : M*K1 bf16
  size_t o1 = o0 + (size_t)M * K1 * 2;      // WaT: N1*K1 bf16
  size_t o2 = o1 + (size_t)N1 * K1 * 2;     // qkv: M*N1 bf16 (V stripe holds Vt remap)
  size_t o3 = o2 + (size_t)M * N1 * 2;      // yb : M*C bf16
  size_t o4 = o3 + (size_t)M * Cdim * 2;    // WpT: C*C bf16

  unsigned short* xb   = (unsigned short*)(ws + o0);
  unsigned short* WaT  = (unsigned short*)(ws + o1);
  unsigned short* qkvb = (unsigned short*)(ws + o2);
  unsigned short* yb   = (unsigned short*)(ws + o3);
  unsigned short* WpT  = (unsigned short*)(ws + o4);

  preamble_kernel<<<dim3(24576), dim3(256), 0, stream>>>(x, Wa, Wp, xb, WaT, WpT);

  // qkv GEMM: grid = 32*24 = 768 blocks; V-region blocks write Vt directly
  gemm_p3<1><<<dim3((M / 128) * (N1 / 256)), dim3(512), 0, stream>>>(
      (const bf16_t*)xb, (const bf16_t*)WaT, (void*)qkvb, N1, K1);

  attn_kernel<<<dim3(Bsz * NH, 8), dim3(512), 0, stream>>>(
      (const bf16_t*)qkvb, yb);

  // proj GEMM: grid = 32*8 = 256 blocks
  gemm_p3<0><<<dim3((M / 128) * (Cdim / 256)), dim3(512), 0, stream>>>(
      (const bf16_t*)yb, (const bf16_t*)WpT, (void*)out, Cdim, K1);
}